// Round 2
// 39.505 us; speedup vs baseline: 1.1582x; 1.1582x over previous
//
#include <hip/hip_runtime.h>
#include <hip/hip_bf16.h>
#include <math.h>

#define BB 64
#define HH 80
#define WW 3000
#define RAD 16
#define TW 96             // output columns per strip
#define NLOAD 128         // loaded columns = TW + 2*16 halo
#define XSW 68            // Xs words/row: 64 data + 4 pad (68 % 32 == 4 -> b128 bank-spread)
#define HXS 116           // Hxp col stride: 112 raw rows + 4 pad (116 % 32 == 20 -> b128 bank-spread)
#define NSTRIP 32         // ceil(3000/96)
#define NT 1024
#define EPSF 1e-8f

#define XS_WORDS (HH * XSW)             // 5440
#define HXP_OFF  XS_WORDS
#define HXP_WORDS (TW * HXS)            // 11136
#define ICH_OFF  (XS_WORDS + HXP_WORDS) // 16576
#define TOT_WORDS (ICH_OFF + HH)        // 16656 words = 66624 B

__device__ __forceinline__ float bflo(uint32_t w) { return __uint_as_float(w << 16); }
__device__ __forceinline__ float bfhi(uint32_t w) { return __uint_as_float(w & 0xffff0000u); }
__device__ __forceinline__ uint32_t packbf2(float lo, float hi) {
    union { __hip_bfloat162 h2; uint32_t u; } u;
    u.h2 = __hip_bfloat162(__float2bfloat16(lo), __float2bfloat16(hi));
    return u.u;
}

// compile-time-folding element selectors (named registers only — no arrays/unions)
#define E4(V, J) ((J) == 0 ? (V).x : ((J) == 1 ? (V).y : ((J) == 2 ? (V).z : (V).w)))
#define W20(Q) E4((Q) < 4 ? v0 : (Q) < 8 ? v1 : (Q) < 12 ? v2 : (Q) < 16 ? v3 : v4, (Q) & 3)
#define W40(Q) E4((Q) < 4 ? v0 : (Q) < 8 ? v1 : (Q) < 12 ? v2 : (Q) < 16 ? v3 : (Q) < 20 ? v4 : \
                  (Q) < 24 ? v5 : (Q) < 28 ? v6 : (Q) < 32 ? v7 : (Q) < 36 ? v8 : v9, (Q) & 3)

__global__ __launch_bounds__(NT, 8)
void localnorm_kernel(const float* __restrict__ in, float* __restrict__ out) {
    extern __shared__ uint32_t smem[];
    uint32_t* Hxp = smem + HXP_OFF;          // Hxp[col][raw_r] at col*HXS + raw_r; raw_r = logical+16
    float* inv_ch = (float*)(smem + ICH_OFF);

    const int t     = threadIdx.x;
    const int strip = blockIdx.x % NSTRIP;
    const int b     = blockIdx.x / NSTRIP;
    const int c0    = strip * TW;

    // phase 0: per-row reciprocals + zero Hxp pad rows (raw 0..15 and 96..111) for all 96 cols
    if (t < HH) {
        int lo = max(t - RAD, 0), hi = min(t + RAD, HH - 1);
        inv_ch[t] = 1.0f / (float)(hi - lo + 1);
    }
    if (t < 768) {
        const int col = t >> 3;
        const int c8  = t & 7;
        const int off = col * HXS + ((c8 < 4) ? (c8 * 4) : (96 + (c8 - 4) * 4));
        *(uint4*)(Hxp + off) = make_uint4(0u, 0u, 0u, 0u);
    }

    // phase 1: load 128 cols x 80 rows, pack to bf16 pairs. 80 rows x 32 quads = 2560 tasks.
    {
        const float* inb = in + (size_t)b * (HH * WW);
        #pragma unroll
        for (int it = 0; it < 3; ++it) {
            const int id = t + it * NT;
            if (it < 2 || id < 2560) {
                const int row = id >> 5;
                const int q   = id & 31;
                const int gc  = c0 - 16 + 4 * q;
                uint2 w2;
                if (gc >= 0 && gc + 4 <= WW) {
                    float4 v = *(const float4*)(inb + (size_t)row * WW + gc);
                    w2.x = packbf2(v.x, v.y);
                    w2.y = packbf2(v.z, v.w);
                } else {
                    float p0 = (gc     >= 0 && gc     < WW) ? inb[(size_t)row * WW + gc]     : 0.f;
                    float p1 = (gc + 1 >= 0 && gc + 1 < WW) ? inb[(size_t)row * WW + gc + 1] : 0.f;
                    float p2 = (gc + 2 >= 0 && gc + 2 < WW) ? inb[(size_t)row * WW + gc + 2] : 0.f;
                    float p3 = (gc + 3 >= 0 && gc + 3 < WW) ? inb[(size_t)row * WW + gc + 3] : 0.f;
                    w2.x = packbf2(p0, p1);
                    w2.y = packbf2(p2, p3);
                }
                *(uint2*)(smem + row * XSW + 2 * q) = w2;
            }
        }
    }
    __syncthreads();

    // phase 2: fused horizontal 33-tap sums of x AND x^2 in one pass over the same registers.
    // 80 rows x 12 segs of 4 word-outputs (8 cols) = 960 threads; 5 b128 reads each.
    {
        const int row = t % HH;
        const int seg = t / HH;
        if (seg < 12) {
            const uint32_t* xr = smem + row * XSW + seg * 4;
            uint4 v0 = *(const uint4*)(xr);
            uint4 v1 = *(const uint4*)(xr + 4);
            uint4 v2 = *(const uint4*)(xr + 8);
            uint4 v3 = *(const uint4*)(xr + 12);
            uint4 v4 = *(const uint4*)(xr + 16);
            // initial window: elements e0..e32 (2-way ILP split)
            float l16 = bflo(W20(16));
            float ax = l16,        bx = 0.f;
            float axx = l16 * l16, bxx = 0.f;
            #pragma unroll
            for (int q = 0; q < 16; q += 2) {
                uint32_t wA = W20(q), wB = W20(q + 1);
                float lA = bflo(wA), hA = bfhi(wA);
                float lB = bflo(wB), hB = bfhi(wB);
                ax  += lA + hA;           bx  += lB + hB;
                axx += lA * lA + hA * hA; bxx += lB * lB + hB * hB;
            }
            ax += bx; axx += bxx;
            uint32_t* hw = Hxp + row + 16;
            #pragma unroll
            for (int k = 0; k < 4; ++k) {
                uint32_t wS = W20(k), wE = W20(k + 16);
                float lS = bflo(wS), hE = bfhi(wE);
                float a1x  = ax - lS + hE;
                float a1xx = axx - lS * lS + hE * hE;
                const int col = 8 * seg + 2 * k;
                hw[col * HXS]       = packbf2(ax, axx);
                hw[(col + 1) * HXS] = packbf2(a1x, a1xx);
                if (k != 3) {
                    float hS = bfhi(wS), lN = bflo(W20(k + 17));
                    ax  = a1x - hS + lN;
                    axx = a1xx - hS * hS + lN * lN;
                }
            }
        }
    }
    __syncthreads();

    // phase 3: vertical 33-tap sums of (Sx, Sxx); mean/var/normalize; direct f32 store.
    // 96 cols x 10 bands of 8 rows = 960 threads; 10 b128 reads each.
    {
        const int c    = t % TW;
        const int band = t / TW;
        const int gc   = c0 + c;
        if (band < 10 && gc < WW) {
            const int r0 = band * 8;                 // logical base row; raw read start = r0
            const uint32_t* hp = Hxp + c * HXS + r0; // raw rows r0 .. r0+39
            uint4 v0 = *(const uint4*)(hp);
            uint4 v1 = *(const uint4*)(hp + 4);
            uint4 v2 = *(const uint4*)(hp + 8);
            uint4 v3 = *(const uint4*)(hp + 12);
            uint4 v4 = *(const uint4*)(hp + 16);
            uint4 v5 = *(const uint4*)(hp + 20);
            uint4 v6 = *(const uint4*)(hp + 24);
            uint4 v7 = *(const uint4*)(hp + 28);
            uint4 v8 = *(const uint4*)(hp + 32);
            uint4 v9 = *(const uint4*)(hp + 36);
            float ax = 0.f, bx = 0.f, axx = 0.f, bxx = 0.f;
            #pragma unroll
            for (int q = 0; q < 32; q += 2) {
                uint32_t wA = W40(q), wB = W40(q + 1);
                ax += bflo(wA); axx += bfhi(wA);
                bx += bflo(wB); bxx += bfhi(wB);
            }
            { uint32_t w = W40(32); ax += bflo(w); axx += bfhi(w); }
            ax += bx; axx += bxx;
            const float icw = 1.0f / (float)(min(gc + RAD, WW - 1) - max(gc - RAD, 0) + 1);
            float4 f4a = *(const float4*)(inv_ch + r0);
            float4 f4b = *(const float4*)(inv_ch + r0 + 4);
            const int  xwoff  = (c + 16) >> 1;
            const bool hiHalf = ((c + 16) & 1) != 0;
            float* outb = out + (size_t)b * (HH * WW);
            #pragma unroll
            for (int k = 0; k < 8; ++k) {
                const int r = r0 + k;
                const float f = E4(k < 4 ? f4a : f4b, k & 3);
                const float ninv = f * icw;
                float mean = ax * ninv;
                float exx  = axx * ninv;
                float var  = fmaxf(exx - mean * mean, 0.f);
                float sd   = __builtin_amdgcn_sqrtf(var);
                uint32_t xw = smem[r * XSW + xwoff];
                float xv = hiHalf ? bfhi(xw) : bflo(xw);
                outb[(size_t)r * WW + gc] = (xv - mean) * __builtin_amdgcn_rcpf(sd + EPSF);
                if (k != 7) {
                    uint32_t wa = W40(k + 33), ws = W40(k);
                    ax  += bflo(wa) - bflo(ws);
                    axx += bfhi(wa) - bfhi(ws);
                }
            }
        }
    }
}

extern "C" void kernel_launch(void* const* d_in, const int* in_sizes, int n_in,
                              void* d_out, int out_size, void* d_ws, size_t ws_size,
                              hipStream_t stream) {
    const float* in = (const float*)d_in[0];
    float* out = (float*)d_out;

    const size_t lds_bytes = (size_t)TOT_WORDS * sizeof(uint32_t);  // 66624
    static bool attr_set = false;
    if (!attr_set) {
        (void)hipFuncSetAttribute((const void*)localnorm_kernel,
                                  hipFuncAttributeMaxDynamicSharedMemorySize,
                                  (int)lds_bytes);
        attr_set = true;
    }

    dim3 grid(BB * NSTRIP);
    dim3 block(NT);
    localnorm_kernel<<<grid, block, lds_bytes, stream>>>(in, out);
}